// Round 3
// baseline (1279.401 us; speedup 1.0000x reference)
//
#include <hip/hip_runtime.h>

#define NPTS 1000000
#define KOFF 27
#define NWG_CONV 7813            // ceil(N/128)
#define NWAVES (NWG_CONV * 4)

typedef __bf16 bf16x8 __attribute__((ext_vector_type(8)));
typedef __bf16 bf16x4 __attribute__((ext_vector_type(4)));
typedef float f32x4 __attribute__((ext_vector_type(4)));

// ---------------- Kernel 1: xb[N+1][64] = bf16(concat(feats, time_emb[batch_idx])) ; row N = 0
__global__ __launch_bounds__(256) void build_x_kernel(
    const float* __restrict__ feats, const float* __restrict__ time_emb,
    const int* __restrict__ batch_idx, __bf16* __restrict__ xb)
{
    const long g = (long)blockIdx.x * 256 + threadIdx.x;
    if (g >= (long)(NPTS + 1) * 16) return;
    const int row = (int)(g >> 4);
    const int c = ((int)g & 15) << 2;
    bf16x4 o;
    if (row < NPTS) {
        f32x4 v;
        if (c < 32) {
            v = __builtin_nontemporal_load((const f32x4*)(feats + (size_t)row * 32 + c));
        } else {
            const int b = batch_idx[row];
            v = *(const f32x4*)(time_emb + (size_t)b * 32 + (c - 32));
        }
        o[0] = (__bf16)v[0]; o[1] = (__bf16)v[1];
        o[2] = (__bf16)v[2]; o[3] = (__bf16)v[3];
    } else {
        o[0] = o[1] = o[2] = o[3] = (__bf16)0.0f;
    }
    *(bf16x4*)(xb + (size_t)row * 64 + c) = o;
}

// ---------------- Kernel 2: WbT[k][cout][cin] = bf16(W[k][cin][cout])
__global__ __launch_bounds__(256) void wtrans_kernel(
    const float* __restrict__ W, __bf16* __restrict__ wbt)
{
    const int g = blockIdx.x * 256 + threadIdx.x;
    if (g >= KOFF * 4096) return;
    const int k = g >> 12;
    const int rem = g & 4095;
    const int co = rem >> 6;
    const int ci = rem & 63;
    wbt[g] = (__bf16)W[(k << 12) + (ci << 6) + co];
}

// ---------------- Kernel 3: gather-GEMM conv, operand-swapped MFMA.
// Pipeline discipline (in-order vmcnt!): per iteration k the program order is
//   [B[k] loads] -> [A-gather issue for k+2] -> [idx prefetch k+3] -> [MFMA k]
// so MFMA's wait for B[k] does NOT retire the k+2 gathers: true depth-2 A pipeline.
// Fully unrolled; all ring indices compile-time.
__global__ __launch_bounds__(256) void conv_kernel(
    const __bf16* __restrict__ xb, const __bf16* __restrict__ wbt,
    const int* __restrict__ nbr_idx, const int* __restrict__ nbr_valid,
    float* __restrict__ out, float* __restrict__ partials)
{
    const int tid  = threadIdx.x;
    const int wave = tid >> 6;
    const int lane = tid & 63;
    const int l15  = lane & 15;
    const int quad = lane >> 4;
    const int R0   = blockIdx.x * 128 + wave * 32;
    const int row0 = R0 + l15;
    const int row1 = row0 + 16;
    const bool ok0 = row0 < NPTS;
    const bool ok1 = row1 < NPTS;
    const int r0c = ok0 ? row0 : NPTS - 1;
    const int r1c = ok1 ? row1 : NPTS - 1;

    f32x4 acc[2][4];
#pragma unroll
    for (int m = 0; m < 2; ++m)
#pragma unroll
        for (int ct = 0; ct < 4; ++ct)
            acc[m][ct] = (f32x4){0.f, 0.f, 0.f, 0.f};

    bf16x8 A[3][4];                 // gather ring: [stage][A0lo,A0hi,A1lo,A1hi]
    int ii0[3], ii1[3], vv0[3], vv1[3];

    // ---- prologue: idx/valid for k=0,1,2 ; A-gathers issued for k=0,1
#pragma unroll
    for (int s = 0; s < 3; ++s) {
        const long kb = (long)s * NPTS;
        ii0[s] = __builtin_nontemporal_load(nbr_idx + kb + r0c);
        ii1[s] = __builtin_nontemporal_load(nbr_idx + kb + r1c);
        vv0[s] = __builtin_nontemporal_load(nbr_valid + kb + r0c);
        vv1[s] = __builtin_nontemporal_load(nbr_valid + kb + r1c);
    }
#pragma unroll
    for (int s = 0; s < 2; ++s) {
        const int g0 = (vv0[s] && ok0) ? ii0[s] : NPTS;
        const int g1 = (vv1[s] && ok1) ? ii1[s] : NPTS;
        const bf16x8* p0 = (const bf16x8*)(xb + (size_t)g0 * 64) + quad;
        const bf16x8* p1 = (const bf16x8*)(xb + (size_t)g1 * 64) + quad;
        A[s][0] = p0[0]; A[s][1] = p0[4]; A[s][2] = p1[0]; A[s][3] = p1[4];
    }

#pragma unroll
    for (int k = 0; k < KOFF; ++k) {
        // ---- (P1) B[k] fragments — issued BEFORE this iteration's gathers
        const bf16x8* wb8 = (const bf16x8*)wbt + (size_t)k * 512 + l15 * 8 + quad;
        bf16x8 b[8];
#pragma unroll
        for (int ct = 0; ct < 4; ++ct) {
            b[2 * ct]     = wb8[ct * 128];
            b[2 * ct + 1] = wb8[ct * 128 + 4];
        }

        // ---- (P2) issue A-gathers for k+2 (stay in flight across MFMA's B-wait)
        if (k + 2 < KOFF) {
            const int s = (k + 2) % 3;
            const int g0 = (vv0[s] && ok0) ? ii0[s] : NPTS;
            const int g1 = (vv1[s] && ok1) ? ii1[s] : NPTS;
            const bf16x8* p0 = (const bf16x8*)(xb + (size_t)g0 * 64) + quad;
            const bf16x8* p1 = (const bf16x8*)(xb + (size_t)g1 * 64) + quad;
            A[s][0] = p0[0]; A[s][1] = p0[4]; A[s][2] = p1[0]; A[s][3] = p1[4];
        }

        // ---- (P3) idx/valid prefetch for k+3 (single-use stream -> nt)
        if (k + 3 < KOFF) {
            const int s = (k + 3) % 3;
            const long kb = (long)(k + 3) * NPTS;
            ii0[s] = __builtin_nontemporal_load(nbr_idx + kb + r0c);
            ii1[s] = __builtin_nontemporal_load(nbr_idx + kb + r1c);
            vv0[s] = __builtin_nontemporal_load(nbr_valid + kb + r0c);
            vv1[s] = __builtin_nontemporal_load(nbr_valid + kb + r1c);
        }

        // ---- (P4) MFMA k: needs A[k%3] (issued >=2 iters ago), B[k] (P1)
        const int s = k % 3;
#pragma unroll
        for (int ct = 0; ct < 4; ++ct) {
            acc[0][ct] = __builtin_amdgcn_mfma_f32_16x16x32_bf16(b[2 * ct],     A[s][0], acc[0][ct], 0, 0, 0);
            acc[0][ct] = __builtin_amdgcn_mfma_f32_16x16x32_bf16(b[2 * ct + 1], A[s][1], acc[0][ct], 0, 0, 0);
            acc[1][ct] = __builtin_amdgcn_mfma_f32_16x16x32_bf16(b[2 * ct],     A[s][2], acc[1][ct], 0, 0, 0);
            acc[1][ct] = __builtin_amdgcn_mfma_f32_16x16x32_bf16(b[2 * ct + 1], A[s][3], acc[1][ct], 0, 0, 0);
        }
    }

    // ---- store pre-BN f32: lane holds couts {ct*16+quad*4..+3} of point (m, l15)
#pragma unroll
    for (int m = 0; m < 2; ++m) {
        const int p = R0 + m * 16 + l15;
        if (p < NPTS) {
            float* pp = out + (size_t)p * 64 + quad * 4;
#pragma unroll
            for (int ct = 0; ct < 4; ++ct)
                *(f32x4*)(pp + ct * 16) = acc[m][ct];
        }
    }

    // ---- BN partials: reduce over the 16 points (l15 lanes) per cout
    const size_t pb = ((size_t)blockIdx.x * 4 + wave) * 128;
#pragma unroll
    for (int ct = 0; ct < 4; ++ct) {
        f32x4 sv, qv;
#pragma unroll
        for (int j = 0; j < 4; ++j) {
            float s  = acc[0][ct][j] + acc[1][ct][j];
            float ss = acc[0][ct][j] * acc[0][ct][j] + acc[1][ct][j] * acc[1][ct][j];
            s += __shfl_xor(s, 1);  ss += __shfl_xor(ss, 1);
            s += __shfl_xor(s, 2);  ss += __shfl_xor(ss, 2);
            s += __shfl_xor(s, 4);  ss += __shfl_xor(ss, 4);
            s += __shfl_xor(s, 8);  ss += __shfl_xor(ss, 8);
            sv[j] = s; qv[j] = ss;
        }
        if (l15 == 0) {
            *(f32x4*)(partials + pb + ct * 16 + quad * 4)      = sv;
            *(f32x4*)(partials + pb + 64 + ct * 16 + quad * 4) = qv;
        }
    }
}

// ---------------- Kernel 4: reduce partials [NWAVES][128] -> p2 [128][128]
__global__ __launch_bounds__(256) void bn_pass1(
    const float* __restrict__ partials, float* __restrict__ p2)
{
    __shared__ float lds[256];
    const int tid = threadIdx.x;
    const int c = tid & 127;
    const int half = tid >> 7;
    float s = 0.f;
    for (int r = blockIdx.x * 2 + half; r < NWAVES; r += 256)
        s += __builtin_nontemporal_load(partials + (size_t)r * 128 + c);
    lds[tid] = s;
    __syncthreads();
    if (tid < 128) p2[blockIdx.x * 128 + tid] = lds[tid] + lds[tid + 128];
}

// ---------------- Kernel 5: finalize BN scale/shift
__global__ void bn_pass2(const float* __restrict__ p2, const float* __restrict__ gamma,
                         const float* __restrict__ beta, float* __restrict__ bn)
{
    __shared__ float lds[128];
    const int t = threadIdx.x;
    float s = 0.f;
    for (int b = 0; b < 128; ++b) s += p2[b * 128 + t];
    lds[t] = s;
    __syncthreads();
    if (t < 64) {
        const float inv_n = 1.0f / (float)NPTS;
        const float mean = lds[t] * inv_n;
        const float var = lds[t + 64] * inv_n - mean * mean;
        const float scale = rsqrtf(var + 1e-5f) * gamma[t];
        bn[t] = scale;
        bn[64 + t] = beta[t] - mean * scale;   // conv bias cancels under BN; omitted
    }
}

// ---------------- Kernel 6: y = silu(pre*scale + shift), in-place on d_out
__global__ __launch_bounds__(256) void bn_silu_kernel(
    float* __restrict__ out, const float* __restrict__ bn)
{
    __shared__ float s[128];
    if (threadIdx.x < 128) s[threadIdx.x] = bn[threadIdx.x];
    __syncthreads();
    f32x4* o4 = (f32x4*)out;
    const long M4 = (long)NPTS * 16;
    for (long i = (long)blockIdx.x * 256 + threadIdx.x; i < M4; i += (long)gridDim.x * 256) {
        const int c0 = ((int)i & 15) << 2;
        f32x4 v = __builtin_nontemporal_load(o4 + i);
#pragma unroll
        for (int j = 0; j < 4; ++j) {
            const float y = v[j] * s[c0 + j] + s[64 + c0 + j];
            v[j] = y * (1.0f / (1.0f + __expf(-y)));
        }
        o4[i] = v;
    }
}

extern "C" void kernel_launch(void* const* d_in, const int* in_sizes, int n_in,
                              void* d_out, int out_size, void* d_ws, size_t ws_size,
                              hipStream_t stream)
{
    const float* feats     = (const float*)d_in[0];
    const float* time_emb  = (const float*)d_in[1];
    const float* W         = (const float*)d_in[2];
    /* d_in[3] = bias: cancels exactly under training-mode BN -> unused */
    const float* gamma     = (const float*)d_in[4];
    const float* beta      = (const float*)d_in[5];
    const int*   batch_idx = (const int*)d_in[6];
    const int*   nbr_idx   = (const int*)d_in[7];
    const int*   nbr_valid = (const int*)d_in[8];
    float* out = (float*)d_out;

    char* ws = (char*)d_ws;
    size_t off = 0;
    __bf16* xb  = (__bf16*)(ws + off); off += (size_t)(NPTS + 1) * 64 * 2;   // 128.0 MB
    __bf16* wbt = (__bf16*)(ws + off); off += (size_t)KOFF * 4096 * 2;       // 216 KB
    float* partials = (float*)(ws + off); off += (size_t)NWAVES * 128 * 4;   // 16.0 MB
    float* p2   = (float*)(ws + off); off += 128 * 128 * 4;                  // 64 KB
    float* bn   = (float*)(ws + off); off += 512;

    hipLaunchKernelGGL(build_x_kernel, dim3(62501), dim3(256), 0, stream,
                       feats, time_emb, batch_idx, xb);
    hipLaunchKernelGGL(wtrans_kernel, dim3(432), dim3(256), 0, stream, W, wbt);
    hipLaunchKernelGGL(conv_kernel, dim3(NWG_CONV), dim3(256), 0, stream,
                       xb, wbt, nbr_idx, nbr_valid, out, partials);
    hipLaunchKernelGGL(bn_pass1, dim3(128), dim3(256), 0, stream, partials, p2);
    hipLaunchKernelGGL(bn_pass2, dim3(1), dim3(128), 0, stream, p2, gamma, beta, bn);
    hipLaunchKernelGGL(bn_silu_kernel, dim3(2048), dim3(256), 0, stream, out, bn);
}

// Round 4
// 783.075 us; speedup vs baseline: 1.6338x; 1.6338x over previous
//
#include <hip/hip_runtime.h>

#define NPTS 1000000
#define KOFF 27
#define NWG_CONV 7813            // ceil(N/128)
#define NWAVES (NWG_CONV * 4)

typedef __bf16 bf16x8 __attribute__((ext_vector_type(8)));
typedef __bf16 bf16x4 __attribute__((ext_vector_type(4)));
typedef float f32x4 __attribute__((ext_vector_type(4)));

// ---------------- Kernel 1: xh[N+1][32] = bf16(feats) ; row N = 0  (the ONLY big gather target, 64 MB)
__global__ __launch_bounds__(256) void build_xh_kernel(
    const float* __restrict__ feats, __bf16* __restrict__ xh)
{
    const long g = (long)blockIdx.x * 256 + threadIdx.x;
    if (g >= (long)(NPTS + 1) * 8) return;
    const int row = (int)(g >> 3);
    const int c = ((int)g & 7) << 2;
    bf16x4 o;
    if (row < NPTS) {
        f32x4 v = __builtin_nontemporal_load((const f32x4*)(feats + (size_t)row * 32 + c));
        o[0] = (__bf16)v[0]; o[1] = (__bf16)v[1];
        o[2] = (__bf16)v[2]; o[3] = (__bf16)v[3];
    } else {
        o[0] = o[1] = o[2] = o[3] = (__bf16)0.0f;
    }
    *(bf16x4*)(xh + (size_t)row * 32 + c) = o;
}

// ---------------- Kernel 2: bidx8[n] = uint8(batch_idx[n]) ; bidx8[N] = 255 (1 MB, L2-resident)
__global__ __launch_bounds__(256) void bidx_pack_kernel(
    const int* __restrict__ batch_idx, unsigned char* __restrict__ b8)
{
    const int n = blockIdx.x * 256 + threadIdx.x;
    if (n > NPTS) return;
    b8[n] = (n < NPTS) ? (unsigned char)batch_idx[n] : (unsigned char)255;
}

// ---------------- Kernel 3: wlo[k][cout][cin0..31] = bf16(W[k][cin][cout])  (feat half only)
__global__ __launch_bounds__(256) void wtrans_lo_kernel(
    const float* __restrict__ W, __bf16* __restrict__ wlo)
{
    const int g = blockIdx.x * 256 + threadIdx.x;
    if (g >= KOFF * 2048) return;
    const int k = g >> 11, rem = g & 2047;
    const int co = rem >> 5, ci = rem & 31;
    wlo[g] = (__bf16)W[k * 4096 + ci * 64 + co];
}

// ---------------- Kernel 4: twb[k][cout][slot] = (slot<8) ? time_emb[slot]·W[k][32:,cout] : 0
// One-hot-MFMA companion table: time-half contribution factorizes over batch (only 8 embeddings).
__global__ __launch_bounds__(256) void tw_kernel(
    const float* __restrict__ time_emb, const float* __restrict__ W,
    __bf16* __restrict__ twb)
{
    const int g = blockIdx.x * 256 + threadIdx.x;
    if (g >= KOFF * 2048) return;
    const int k = g >> 11, rem = g & 2047;
    const int co = rem >> 5, slot = rem & 31;
    float v = 0.f;
    if (slot < 8) {
#pragma unroll
        for (int ci = 0; ci < 32; ++ci)
            v += time_emb[slot * 32 + ci] * W[k * 4096 + (32 + ci) * 64 + co];
    }
    twb[g] = (__bf16)v;
}

// ---------------- Kernel 5: gather-GEMM conv (feat-half gather + one-hot time MFMA)
// Per iter k: [W/tw frags k] -> [gathers k+2] -> [idx prefetch k+3] -> [one-hot + MFMA k]
// In-order vmcnt: MFMA's wait retires nothing issued after P1 -> depth-2 gather pipeline.
template <int BF16PRE>
__global__ __launch_bounds__(256) void conv_kernel(
    const __bf16* __restrict__ xh, const unsigned char* __restrict__ b8,
    const __bf16* __restrict__ wlo, const __bf16* __restrict__ twb,
    const int* __restrict__ nbr_idx, const int* __restrict__ nbr_valid,
    float* __restrict__ outf, __bf16* __restrict__ pre,
    float* __restrict__ partials)
{
    const int tid  = threadIdx.x;
    const int wave = tid >> 6;
    const int lane = tid & 63;
    const int l15  = lane & 15;
    const int quad = lane >> 4;
    const int R0   = blockIdx.x * 128 + wave * 32;
    const int row0 = R0 + l15;
    const int row1 = row0 + 16;
    const bool ok0 = row0 < NPTS;
    const bool ok1 = row1 < NPTS;
    const int r0c = ok0 ? row0 : NPTS - 1;
    const int r1c = ok1 ? row1 : NPTS - 1;

    f32x4 acc[2][4];
#pragma unroll
    for (int m = 0; m < 2; ++m)
#pragma unroll
        for (int ct = 0; ct < 4; ++ct)
            acc[m][ct] = (f32x4){0.f, 0.f, 0.f, 0.f};

    bf16x8 X0[3], X1[3];            // gathered feat fragments (16B: cin quad*8..+7)
    int B0v[3], B1v[3];             // gathered batch bytes
    int ii0[3], ii1[3], vv0[3], vv1[3];

    // ---- prologue: idx/valid for k=0,1,2 ; gathers for k=0,1
#pragma unroll
    for (int s = 0; s < 3; ++s) {
        const long kb = (long)s * NPTS;
        ii0[s] = __builtin_nontemporal_load(nbr_idx + kb + r0c);
        ii1[s] = __builtin_nontemporal_load(nbr_idx + kb + r1c);
        vv0[s] = __builtin_nontemporal_load(nbr_valid + kb + r0c);
        vv1[s] = __builtin_nontemporal_load(nbr_valid + kb + r1c);
    }
#pragma unroll
    for (int s = 0; s < 2; ++s) {
        const int g0 = (vv0[s] && ok0) ? ii0[s] : NPTS;
        const int g1 = (vv1[s] && ok1) ? ii1[s] : NPTS;
        X0[s] = *(const bf16x8*)(xh + (size_t)g0 * 32 + quad * 8);
        X1[s] = *(const bf16x8*)(xh + (size_t)g1 * 32 + quad * 8);
        B0v[s] = b8[g0]; B1v[s] = b8[g1];
    }

    const __bf16 onebf = (__bf16)1.0f;
    const __bf16 zbf   = (__bf16)0.0f;

#pragma unroll
    for (int k = 0; k < KOFF; ++k) {
        // ---- (P1) W / tw fragments for k (first: MFMA's wait won't drain later gathers)
        const bf16x8* wk = (const bf16x8*)(wlo + (size_t)k * 2048);
        const bf16x8* tk = (const bf16x8*)(twb + (size_t)k * 2048);
        bf16x8 wf[4], tf[4];
#pragma unroll
        for (int ct = 0; ct < 4; ++ct) {
            const int cidx = (ct * 16 + l15) * 4 + quad;
            wf[ct] = wk[cidx];
            tf[ct] = tk[cidx];
        }

        // ---- (P2) issue gathers for k+2
        if (k + 2 < KOFF) {
            const int s = (k + 2) % 3;
            const int g0 = (vv0[s] && ok0) ? ii0[s] : NPTS;
            const int g1 = (vv1[s] && ok1) ? ii1[s] : NPTS;
            X0[s] = *(const bf16x8*)(xh + (size_t)g0 * 32 + quad * 8);
            X1[s] = *(const bf16x8*)(xh + (size_t)g1 * 32 + quad * 8);
            B0v[s] = b8[g0]; B1v[s] = b8[g1];
        }

        // ---- (P3) idx/valid prefetch for k+3
        if (k + 3 < KOFF) {
            const int s = (k + 3) % 3;
            const long kb = (long)(k + 3) * NPTS;
            ii0[s] = __builtin_nontemporal_load(nbr_idx + kb + r0c);
            ii1[s] = __builtin_nontemporal_load(nbr_idx + kb + r1c);
            vv0[s] = __builtin_nontemporal_load(nbr_valid + kb + r0c);
            vv1[s] = __builtin_nontemporal_load(nbr_valid + kb + r1c);
        }

        // ---- (P4) one-hot batch fragments + MFMA
        const int s = k % 3;
        const int m0 = (quad == 0) ? B0v[s] : 8;   // only quad0 lanes carry k-slices 0..7
        const int m1 = (quad == 1 - 1) ? B1v[s] : 8;
        bf16x8 oh0, oh1;
#pragma unroll
        for (int j = 0; j < 8; ++j) {
            oh0[j] = (m0 == j) ? onebf : zbf;
            oh1[j] = (m1 == j) ? onebf : zbf;
        }
#pragma unroll
        for (int ct = 0; ct < 4; ++ct) {
            acc[0][ct] = __builtin_amdgcn_mfma_f32_16x16x32_bf16(wf[ct], X0[s], acc[0][ct], 0, 0, 0);
            acc[1][ct] = __builtin_amdgcn_mfma_f32_16x16x32_bf16(wf[ct], X1[s], acc[1][ct], 0, 0, 0);
            acc[0][ct] = __builtin_amdgcn_mfma_f32_16x16x32_bf16(tf[ct], oh0, acc[0][ct], 0, 0, 0);
            acc[1][ct] = __builtin_amdgcn_mfma_f32_16x16x32_bf16(tf[ct], oh1, acc[1][ct], 0, 0, 0);
        }
    }

    // ---- store pre-BN: lane holds couts {ct*16+quad*4..+3} of point (m, l15)
#pragma unroll
    for (int m = 0; m < 2; ++m) {
        const int p = R0 + m * 16 + l15;
        if (p < NPTS) {
            if (BF16PRE) {
                __bf16* pp = pre + (size_t)p * 64 + quad * 4;
#pragma unroll
                for (int ct = 0; ct < 4; ++ct) {
                    const f32x4 a = acc[m][ct];
                    bf16x4 o;
                    o[0] = (__bf16)a[0]; o[1] = (__bf16)a[1];
                    o[2] = (__bf16)a[2]; o[3] = (__bf16)a[3];
                    *(bf16x4*)(pp + ct * 16) = o;
                }
            } else {
                float* pp = outf + (size_t)p * 64 + quad * 4;
#pragma unroll
                for (int ct = 0; ct < 4; ++ct)
                    *(f32x4*)(pp + ct * 16) = acc[m][ct];
            }
        }
    }

    // ---- BN partials: reduce over the 16 points (l15 lanes) per cout
    const size_t pb = ((size_t)blockIdx.x * 4 + wave) * 128;
#pragma unroll
    for (int ct = 0; ct < 4; ++ct) {
        f32x4 sv, qv;
#pragma unroll
        for (int j = 0; j < 4; ++j) {
            float s  = acc[0][ct][j] + acc[1][ct][j];
            float ss = acc[0][ct][j] * acc[0][ct][j] + acc[1][ct][j] * acc[1][ct][j];
            s += __shfl_xor(s, 1);  ss += __shfl_xor(ss, 1);
            s += __shfl_xor(s, 2);  ss += __shfl_xor(ss, 2);
            s += __shfl_xor(s, 4);  ss += __shfl_xor(ss, 4);
            s += __shfl_xor(s, 8);  ss += __shfl_xor(ss, 8);
            sv[j] = s; qv[j] = ss;
        }
        if (l15 == 0) {
            *(f32x4*)(partials + pb + ct * 16 + quad * 4)      = sv;
            *(f32x4*)(partials + pb + 64 + ct * 16 + quad * 4) = qv;
        }
    }
}

// ---------------- Kernel 6: reduce partials [NWAVES][128] -> p2 [128][128]
__global__ __launch_bounds__(256) void bn_pass1(
    const float* __restrict__ partials, float* __restrict__ p2)
{
    __shared__ float lds[256];
    const int tid = threadIdx.x;
    const int c = tid & 127;
    const int half = tid >> 7;
    float s = 0.f;
    for (int r = blockIdx.x * 2 + half; r < NWAVES; r += 256)
        s += __builtin_nontemporal_load(partials + (size_t)r * 128 + c);
    lds[tid] = s;
    __syncthreads();
    if (tid < 128) p2[blockIdx.x * 128 + tid] = lds[tid] + lds[tid + 128];
}

// ---------------- Kernel 7: finalize BN scale/shift
__global__ void bn_pass2(const float* __restrict__ p2, const float* __restrict__ gamma,
                         const float* __restrict__ beta, float* __restrict__ bn)
{
    __shared__ float lds[128];
    const int t = threadIdx.x;
    float s = 0.f;
    for (int b = 0; b < 128; ++b) s += p2[b * 128 + t];
    lds[t] = s;
    __syncthreads();
    if (t < 64) {
        const float inv_n = 1.0f / (float)NPTS;
        const float mean = lds[t] * inv_n;
        const float var = lds[t + 64] * inv_n - mean * mean;
        const float scale = rsqrtf(var + 1e-5f) * gamma[t];
        bn[t] = scale;
        bn[64 + t] = beta[t] - mean * scale;   // conv bias cancels under BN; omitted
    }
}

// ---------------- Kernel 8a: y = silu(pre_bf16*scale + shift) -> f32 d_out
__global__ __launch_bounds__(256) void bn_silu_bf16_kernel(
    const __bf16* __restrict__ pre, float* __restrict__ out, const float* __restrict__ bn)
{
    __shared__ float s[128];
    if (threadIdx.x < 128) s[threadIdx.x] = bn[threadIdx.x];
    __syncthreads();
    const long M8 = (long)NPTS * 8;
    for (long i = (long)blockIdx.x * 256 + threadIdx.x; i < M8; i += (long)gridDim.x * 256) {
        const int c0 = ((int)i & 7) << 3;
        const bf16x8 v = __builtin_nontemporal_load((const bf16x8*)pre + i);
        f32x4 lo, hi;
#pragma unroll
        for (int j = 0; j < 4; ++j) {
            const float y = (float)v[j] * s[c0 + j] + s[64 + c0 + j];
            lo[j] = y * (1.0f / (1.0f + __expf(-y)));
        }
#pragma unroll
        for (int j = 0; j < 4; ++j) {
            const float y = (float)v[4 + j] * s[c0 + 4 + j] + s[64 + c0 + 4 + j];
            hi[j] = y * (1.0f / (1.0f + __expf(-y)));
        }
        f32x4* o = (f32x4*)out + i * 2;
        o[0] = lo; o[1] = hi;
    }
}

// ---------------- Kernel 8b: fallback, f32 pre-BN in-place on d_out
__global__ __launch_bounds__(256) void bn_silu_f32_kernel(
    float* __restrict__ out, const float* __restrict__ bn)
{
    __shared__ float s[128];
    if (threadIdx.x < 128) s[threadIdx.x] = bn[threadIdx.x];
    __syncthreads();
    f32x4* o4 = (f32x4*)out;
    const long M4 = (long)NPTS * 16;
    for (long i = (long)blockIdx.x * 256 + threadIdx.x; i < M4; i += (long)gridDim.x * 256) {
        const int c0 = ((int)i & 15) << 2;
        f32x4 v = __builtin_nontemporal_load(o4 + i);
#pragma unroll
        for (int j = 0; j < 4; ++j) {
            const float y = v[j] * s[c0 + j] + s[64 + c0 + j];
            v[j] = y * (1.0f / (1.0f + __expf(-y)));
        }
        o4[i] = v;
    }
}

extern "C" void kernel_launch(void* const* d_in, const int* in_sizes, int n_in,
                              void* d_out, int out_size, void* d_ws, size_t ws_size,
                              hipStream_t stream)
{
    const float* feats     = (const float*)d_in[0];
    const float* time_emb  = (const float*)d_in[1];
    const float* W         = (const float*)d_in[2];
    /* d_in[3] = bias: cancels exactly under training-mode BN -> unused */
    const float* gamma     = (const float*)d_in[4];
    const float* beta      = (const float*)d_in[5];
    const int*   batch_idx = (const int*)d_in[6];
    const int*   nbr_idx   = (const int*)d_in[7];
    const int*   nbr_valid = (const int*)d_in[8];
    float* out = (float*)d_out;

    char* ws = (char*)d_ws;
    size_t off = 0;
    auto take = [&](size_t bytes) { char* p = ws + off; off = (off + bytes + 255) & ~(size_t)255; return p; };
    __bf16* xh         = (__bf16*)take((size_t)(NPTS + 1) * 32 * 2);     // 64 MB
    unsigned char* b8  = (unsigned char*)take(NPTS + 1);                 // 1 MB
    __bf16* wlo        = (__bf16*)take((size_t)KOFF * 2048 * 2);         // 108 KB
    __bf16* twb        = (__bf16*)take((size_t)KOFF * 2048 * 2);         // 108 KB
    float* partials    = (float*)take((size_t)NWAVES * 128 * 4);         // 16 MB
    float* p2          = (float*)take(128 * 128 * 4);
    float* bn          = (float*)take(512);
    const size_t pre_bytes = (size_t)NPTS * 64 * 2;                      // 128 MB
    const bool bf16pre = (off + pre_bytes) <= ws_size;
    __bf16* pre = bf16pre ? (__bf16*)take(pre_bytes) : (__bf16*)0;

    hipLaunchKernelGGL(build_xh_kernel, dim3(31251), dim3(256), 0, stream, feats, xh);
    hipLaunchKernelGGL(bidx_pack_kernel, dim3(3907), dim3(256), 0, stream, batch_idx, b8);
    hipLaunchKernelGGL(wtrans_lo_kernel, dim3(216), dim3(256), 0, stream, W, wlo);
    hipLaunchKernelGGL(tw_kernel, dim3(216), dim3(256), 0, stream, time_emb, W, twb);
    if (bf16pre) {
        hipLaunchKernelGGL((conv_kernel<1>), dim3(NWG_CONV), dim3(256), 0, stream,
                           xh, b8, wlo, twb, nbr_idx, nbr_valid, out, pre, partials);
    } else {
        hipLaunchKernelGGL((conv_kernel<0>), dim3(NWG_CONV), dim3(256), 0, stream,
                           xh, b8, wlo, twb, nbr_idx, nbr_valid, out, pre, partials);
    }
    hipLaunchKernelGGL(bn_pass1, dim3(128), dim3(256), 0, stream, partials, p2);
    hipLaunchKernelGGL(bn_pass2, dim3(1), dim3(128), 0, stream, p2, gamma, beta, bn);
    if (bf16pre) {
        hipLaunchKernelGGL(bn_silu_bf16_kernel, dim3(2048), dim3(256), 0, stream, pre, out, bn);
    } else {
        hipLaunchKernelGGL(bn_silu_f32_kernel, dim3(2048), dim3(256), 0, stream, out, bn);
    }
}

// Round 5
// 705.709 us; speedup vs baseline: 1.8129x; 1.1096x over previous
//
#include <hip/hip_runtime.h>

#define NPTS 1000000
#define KOFF 27
#define NWG_CONV 7813            // ceil(N/128)
#define NWAVES (NWG_CONV * 4)

typedef __bf16 bf16x8 __attribute__((ext_vector_type(8)));
typedef __bf16 bf16x4 __attribute__((ext_vector_type(4)));
typedef float f32x4 __attribute__((ext_vector_type(4)));

// ---------------- Kernel 1: xh[N][32] = bf16(feats)  (the ONLY gather target, 64 MB)
__global__ __launch_bounds__(256) void build_xh_kernel(
    const float* __restrict__ feats, __bf16* __restrict__ xh)
{
    const long g = (long)blockIdx.x * 256 + threadIdx.x;
    if (g >= (long)NPTS * 8) return;
    const int row = (int)(g >> 3);
    const int c = ((int)g & 7) << 2;
    f32x4 v = __builtin_nontemporal_load((const f32x4*)(feats + (size_t)row * 32 + c));
    bf16x4 o;
    o[0] = (__bf16)v[0]; o[1] = (__bf16)v[1];
    o[2] = (__bf16)v[2]; o[3] = (__bf16)v[3];
    *(bf16x4*)(xh + (size_t)row * 32 + c) = o;
}

// ---------------- Kernel 2: batch boundaries. batch_idx is SORTED -> batch(g) from 7 thresholds.
// bounds[j] = first index with batch_idx >= j  (j=1..7); bounds[0]=0, bounds[8]=N.
__global__ void bounds_kernel(const int* __restrict__ batch_idx, int* __restrict__ bounds)
{
    const int j = threadIdx.x;
    if (j > 8) return;
    if (j == 0) { bounds[0] = 0; return; }
    if (j == 8) { bounds[8] = NPTS; return; }
    int lo = 0, hi = NPTS;
    while (lo < hi) {
        const int mid = (lo + hi) >> 1;
        if (batch_idx[mid] < j) lo = mid + 1; else hi = mid;
    }
    bounds[j] = lo;
}

// ---------------- Kernel 3: wlo[k][cout][cin0..31] = bf16(W[k][cin][cout])  (feat half)
__global__ __launch_bounds__(256) void wtrans_lo_kernel(
    const float* __restrict__ W, __bf16* __restrict__ wlo)
{
    const int g = blockIdx.x * 256 + threadIdx.x;
    if (g >= KOFF * 2048) return;
    const int k = g >> 11, rem = g & 2047;
    const int co = rem >> 5, ci = rem & 31;
    wlo[g] = (__bf16)W[k * 4096 + ci * 64 + co];
}

// ---------------- Kernel 4: twb[k][cout][slot] = (slot<8) ? time_emb[slot]·W[k][32:,cout] : 0
__global__ __launch_bounds__(256) void tw_kernel(
    const float* __restrict__ time_emb, const float* __restrict__ W,
    __bf16* __restrict__ twb)
{
    const int g = blockIdx.x * 256 + threadIdx.x;
    if (g >= KOFF * 2048) return;
    const int k = g >> 11, rem = g & 2047;
    const int co = rem >> 5, slot = rem & 31;
    float v = 0.f;
    if (slot < 8) {
#pragma unroll
        for (int ci = 0; ci < 32; ++ci)
            v += time_emb[slot * 32 + ci] * W[k * 4096 + (32 + ci) * 64 + co];
    }
    twb[g] = (__bf16)v;
}

__device__ __forceinline__ int batch_of(int g, int t1, int t2, int t3, int t4,
                                        int t5, int t6, int t7)
{
    return (g >= t1) + (g >= t2) + (g >= t3) + (g >= t4) +
           (g >= t5) + (g >= t6) + (g >= t7);
}

// ---------------- Kernel 5: gather-GEMM conv.
// Requests minimized: no b8 gather (thresholds), invalid gathers exec-masked off.
// Rings: X depth-4 (3 gathers in flight), idx depth-8 (distance-6 prefetch so the
// gather address never waits on the idx stream). Fully unrolled, static ring idx.
template <int BF16PRE>
__global__ __launch_bounds__(256) void conv_kernel(
    const __bf16* __restrict__ xh, const int* __restrict__ bounds,
    const __bf16* __restrict__ wlo, const __bf16* __restrict__ twb,
    const int* __restrict__ nbr_idx, const int* __restrict__ nbr_valid,
    float* __restrict__ outf, __bf16* __restrict__ pre,
    float* __restrict__ partials)
{
    const int tid  = threadIdx.x;
    const int wave = tid >> 6;
    const int lane = tid & 63;
    const int l15  = lane & 15;
    const int quad = lane >> 4;
    const int R0   = blockIdx.x * 128 + wave * 32;
    const int row0 = R0 + l15;
    const int row1 = row0 + 16;
    const bool ok0 = row0 < NPTS;
    const bool ok1 = row1 < NPTS;
    const int r0c = ok0 ? row0 : NPTS - 1;
    const int r1c = ok1 ? row1 : NPTS - 1;

    const int t1 = __builtin_amdgcn_readfirstlane(bounds[1]);
    const int t2 = __builtin_amdgcn_readfirstlane(bounds[2]);
    const int t3 = __builtin_amdgcn_readfirstlane(bounds[3]);
    const int t4 = __builtin_amdgcn_readfirstlane(bounds[4]);
    const int t5 = __builtin_amdgcn_readfirstlane(bounds[5]);
    const int t6 = __builtin_amdgcn_readfirstlane(bounds[6]);
    const int t7 = __builtin_amdgcn_readfirstlane(bounds[7]);

    f32x4 acc[2][4];
#pragma unroll
    for (int m = 0; m < 2; ++m)
#pragma unroll
        for (int ct = 0; ct < 4; ++ct)
            acc[m][ct] = (f32x4){0.f, 0.f, 0.f, 0.f};

    bf16x8 X0[4], X1[4];            // gathered feat fragments, ring of 4
    int M0[4], M1[4];               // batch slot (0..7) or 8 = no time contribution
    int ii0[8], ii1[8], vv0[8], vv1[8];   // idx/valid stream ring of 8

    const bf16x8 zero8 = {};

    // ---- prologue: idx/valid for k=0..5 ; gathers for k=0,1,2
#pragma unroll
    for (int s = 0; s < 6; ++s) {
        const long kb = (long)s * NPTS;
        ii0[s] = __builtin_nontemporal_load(nbr_idx + kb + r0c);
        ii1[s] = __builtin_nontemporal_load(nbr_idx + kb + r1c);
        vv0[s] = __builtin_nontemporal_load(nbr_valid + kb + r0c);
        vv1[s] = __builtin_nontemporal_load(nbr_valid + kb + r1c);
    }
#pragma unroll
    for (int s = 0; s < 3; ++s) {
        const int g0 = ii0[s], g1 = ii1[s];
        const bool va0 = vv0[s] && ok0;
        const bool va1 = vv1[s] && ok1;
        bf16x8 x0 = zero8, x1 = zero8;
        if (va0) x0 = *(const bf16x8*)(xh + (size_t)g0 * 32 + quad * 8);
        if (va1) x1 = *(const bf16x8*)(xh + (size_t)g1 * 32 + quad * 8);
        X0[s] = x0; X1[s] = x1;
        M0[s] = va0 ? batch_of(g0, t1, t2, t3, t4, t5, t6, t7) : 8;
        M1[s] = va1 ? batch_of(g1, t1, t2, t3, t4, t5, t6, t7) : 8;
    }

    const __bf16 onebf = (__bf16)1.0f;
    const __bf16 zbf   = (__bf16)0.0f;

#pragma unroll
    for (int k = 0; k < KOFF; ++k) {
        // ---- (P1) W / tw fragments for k (first in program order: MFMA's vmcnt
        //      wait for these retires nothing issued below)
        const bf16x8* wk = (const bf16x8*)(wlo + (size_t)k * 2048);
        const bf16x8* tk = (const bf16x8*)(twb + (size_t)k * 2048);
        bf16x8 wf[4], tf[4];
#pragma unroll
        for (int ct = 0; ct < 4; ++ct) {
            const int cidx = (ct * 16 + l15) * 4 + quad;
            wf[ct] = wk[cidx];
            tf[ct] = tk[cidx];
        }

        // ---- (P2) issue gathers for k+3 (exec-masked: only valid lanes request)
        if (k + 3 < KOFF) {
            const int s = (k + 3) & 3;
            const int si = (k + 3) & 7;
            const int g0 = ii0[si], g1 = ii1[si];
            const bool va0 = vv0[si] && ok0;
            const bool va1 = vv1[si] && ok1;
            bf16x8 x0 = zero8, x1 = zero8;
            if (va0) x0 = *(const bf16x8*)(xh + (size_t)g0 * 32 + quad * 8);
            if (va1) x1 = *(const bf16x8*)(xh + (size_t)g1 * 32 + quad * 8);
            X0[s] = x0; X1[s] = x1;
            M0[s] = va0 ? batch_of(g0, t1, t2, t3, t4, t5, t6, t7) : 8;
            M1[s] = va1 ? batch_of(g1, t1, t2, t3, t4, t5, t6, t7) : 8;
        }

        // ---- (P3) idx/valid prefetch for k+6
        if (k + 6 < KOFF) {
            const int si = (k + 6) & 7;
            const long kb = (long)(k + 6) * NPTS;
            ii0[si] = __builtin_nontemporal_load(nbr_idx + kb + r0c);
            ii1[si] = __builtin_nontemporal_load(nbr_idx + kb + r1c);
            vv0[si] = __builtin_nontemporal_load(nbr_valid + kb + r0c);
            vv1[si] = __builtin_nontemporal_load(nbr_valid + kb + r1c);
        }

        // ---- (P4) one-hot time fragments + MFMA k
        const int s = k & 3;
        const int m0 = (quad == 0) ? M0[s] : 8;
        const int m1 = (quad == 0) ? M1[s] : 8;
        bf16x8 oh0, oh1;
#pragma unroll
        for (int j = 0; j < 8; ++j) {
            oh0[j] = (m0 == j) ? onebf : zbf;
            oh1[j] = (m1 == j) ? onebf : zbf;
        }
#pragma unroll
        for (int ct = 0; ct < 4; ++ct) {
            acc[0][ct] = __builtin_amdgcn_mfma_f32_16x16x32_bf16(wf[ct], X0[s], acc[0][ct], 0, 0, 0);
            acc[1][ct] = __builtin_amdgcn_mfma_f32_16x16x32_bf16(wf[ct], X1[s], acc[1][ct], 0, 0, 0);
            acc[0][ct] = __builtin_amdgcn_mfma_f32_16x16x32_bf16(tf[ct], oh0, acc[0][ct], 0, 0, 0);
            acc[1][ct] = __builtin_amdgcn_mfma_f32_16x16x32_bf16(tf[ct], oh1, acc[1][ct], 0, 0, 0);
        }
    }

    // ---- store pre-BN: lane holds couts {ct*16+quad*4..+3} of point (m, l15)
#pragma unroll
    for (int m = 0; m < 2; ++m) {
        const int p = R0 + m * 16 + l15;
        if (p < NPTS) {
            if (BF16PRE) {
                __bf16* pp = pre + (size_t)p * 64 + quad * 4;
#pragma unroll
                for (int ct = 0; ct < 4; ++ct) {
                    const f32x4 a = acc[m][ct];
                    bf16x4 o;
                    o[0] = (__bf16)a[0]; o[1] = (__bf16)a[1];
                    o[2] = (__bf16)a[2]; o[3] = (__bf16)a[3];
                    *(bf16x4*)(pp + ct * 16) = o;
                }
            } else {
                float* pp = outf + (size_t)p * 64 + quad * 4;
#pragma unroll
                for (int ct = 0; ct < 4; ++ct)
                    *(f32x4*)(pp + ct * 16) = acc[m][ct];
            }
        }
    }

    // ---- BN partials: reduce over the 16 points (l15 lanes) per cout
    const size_t pb = ((size_t)blockIdx.x * 4 + wave) * 128;
#pragma unroll
    for (int ct = 0; ct < 4; ++ct) {
        f32x4 sv, qv;
#pragma unroll
        for (int j = 0; j < 4; ++j) {
            float s  = acc[0][ct][j] + acc[1][ct][j];
            float ss = acc[0][ct][j] * acc[0][ct][j] + acc[1][ct][j] * acc[1][ct][j];
            s += __shfl_xor(s, 1);  ss += __shfl_xor(ss, 1);
            s += __shfl_xor(s, 2);  ss += __shfl_xor(ss, 2);
            s += __shfl_xor(s, 4);  ss += __shfl_xor(ss, 4);
            s += __shfl_xor(s, 8);  ss += __shfl_xor(ss, 8);
            sv[j] = s; qv[j] = ss;
        }
        if (l15 == 0) {
            *(f32x4*)(partials + pb + ct * 16 + quad * 4)      = sv;
            *(f32x4*)(partials + pb + 64 + ct * 16 + quad * 4) = qv;
        }
    }
}

// ---------------- Kernel 6: reduce partials [NWAVES][128] -> p2 [128][128]
__global__ __launch_bounds__(256) void bn_pass1(
    const float* __restrict__ partials, float* __restrict__ p2)
{
    __shared__ float lds[256];
    const int tid = threadIdx.x;
    const int c = tid & 127;
    const int half = tid >> 7;
    float s = 0.f;
    for (int r = blockIdx.x * 2 + half; r < NWAVES; r += 256)
        s += __builtin_nontemporal_load(partials + (size_t)r * 128 + c);
    lds[tid] = s;
    __syncthreads();
    if (tid < 128) p2[blockIdx.x * 128 + tid] = lds[tid] + lds[tid + 128];
}

// ---------------- Kernel 7: finalize BN scale/shift
__global__ void bn_pass2(const float* __restrict__ p2, const float* __restrict__ gamma,
                         const float* __restrict__ beta, float* __restrict__ bn)
{
    __shared__ float lds[128];
    const int t = threadIdx.x;
    float s = 0.f;
    for (int b = 0; b < 128; ++b) s += p2[b * 128 + t];
    lds[t] = s;
    __syncthreads();
    if (t < 64) {
        const float inv_n = 1.0f / (float)NPTS;
        const float mean = lds[t] * inv_n;
        const float var = lds[t + 64] * inv_n - mean * mean;
        const float scale = rsqrtf(var + 1e-5f) * gamma[t];
        bn[t] = scale;
        bn[64 + t] = beta[t] - mean * scale;   // conv bias cancels under BN; omitted
    }
}

// ---------------- Kernel 8a: y = silu(pre_bf16*scale + shift) -> f32 d_out
__global__ __launch_bounds__(256) void bn_silu_bf16_kernel(
    const __bf16* __restrict__ pre, float* __restrict__ out, const float* __restrict__ bn)
{
    __shared__ float s[128];
    if (threadIdx.x < 128) s[threadIdx.x] = bn[threadIdx.x];
    __syncthreads();
    const long M8 = (long)NPTS * 8;
    for (long i = (long)blockIdx.x * 256 + threadIdx.x; i < M8; i += (long)gridDim.x * 256) {
        const int c0 = ((int)i & 7) << 3;
        const bf16x8 v = __builtin_nontemporal_load((const bf16x8*)pre + i);
        f32x4 lo, hi;
#pragma unroll
        for (int j = 0; j < 4; ++j) {
            const float y = (float)v[j] * s[c0 + j] + s[64 + c0 + j];
            lo[j] = y * (1.0f / (1.0f + __expf(-y)));
        }
#pragma unroll
        for (int j = 0; j < 4; ++j) {
            const float y = (float)v[4 + j] * s[c0 + 4 + j] + s[64 + c0 + 4 + j];
            hi[j] = y * (1.0f / (1.0f + __expf(-y)));
        }
        f32x4* o = (f32x4*)out + i * 2;
        o[0] = lo; o[1] = hi;
    }
}

// ---------------- Kernel 8b: fallback, f32 pre-BN in-place on d_out
__global__ __launch_bounds__(256) void bn_silu_f32_kernel(
    float* __restrict__ out, const float* __restrict__ bn)
{
    __shared__ float s[128];
    if (threadIdx.x < 128) s[threadIdx.x] = bn[threadIdx.x];
    __syncthreads();
    f32x4* o4 = (f32x4*)out;
    const long M4 = (long)NPTS * 16;
    for (long i = (long)blockIdx.x * 256 + threadIdx.x; i < M4; i += (long)gridDim.x * 256) {
        const int c0 = ((int)i & 15) << 2;
        f32x4 v = __builtin_nontemporal_load(o4 + i);
#pragma unroll
        for (int j = 0; j < 4; ++j) {
            const float y = v[j] * s[c0 + j] + s[64 + c0 + j];
            v[j] = y * (1.0f / (1.0f + __expf(-y)));
        }
        o4[i] = v;
    }
}

extern "C" void kernel_launch(void* const* d_in, const int* in_sizes, int n_in,
                              void* d_out, int out_size, void* d_ws, size_t ws_size,
                              hipStream_t stream)
{
    const float* feats     = (const float*)d_in[0];
    const float* time_emb  = (const float*)d_in[1];
    const float* W         = (const float*)d_in[2];
    /* d_in[3] = bias: cancels exactly under training-mode BN -> unused */
    const float* gamma     = (const float*)d_in[4];
    const float* beta      = (const float*)d_in[5];
    const int*   batch_idx = (const int*)d_in[6];
    const int*   nbr_idx   = (const int*)d_in[7];
    const int*   nbr_valid = (const int*)d_in[8];
    float* out = (float*)d_out;

    char* ws = (char*)d_ws;
    size_t off = 0;
    auto take = [&](size_t bytes) { char* p = ws + off; off = (off + bytes + 255) & ~(size_t)255; return p; };
    __bf16* xh      = (__bf16*)take((size_t)NPTS * 32 * 2);          // 64 MB
    int* bounds     = (int*)take(9 * 4);
    __bf16* wlo     = (__bf16*)take((size_t)KOFF * 2048 * 2);        // 108 KB
    __bf16* twb     = (__bf16*)take((size_t)KOFF * 2048 * 2);        // 108 KB
    float* partials = (float*)take((size_t)NWAVES * 128 * 4);        // 16 MB
    float* p2       = (float*)take(128 * 128 * 4);
    float* bn       = (float*)take(512);
    const size_t pre_bytes = (size_t)NPTS * 64 * 2;                  // 128 MB
    const bool bf16pre = (off + pre_bytes) <= ws_size;
    __bf16* pre = bf16pre ? (__bf16*)take(pre_bytes) : (__bf16*)0;

    hipLaunchKernelGGL(build_xh_kernel, dim3(31250), dim3(256), 0, stream, feats, xh);
    hipLaunchKernelGGL(bounds_kernel, dim3(1), dim3(64), 0, stream, batch_idx, bounds);
    hipLaunchKernelGGL(wtrans_lo_kernel, dim3(216), dim3(256), 0, stream, W, wlo);
    hipLaunchKernelGGL(tw_kernel, dim3(216), dim3(256), 0, stream, time_emb, W, twb);
    if (bf16pre) {
        hipLaunchKernelGGL((conv_kernel<1>), dim3(NWG_CONV), dim3(256), 0, stream,
                           xh, bounds, wlo, twb, nbr_idx, nbr_valid, out, pre, partials);
    } else {
        hipLaunchKernelGGL((conv_kernel<0>), dim3(NWG_CONV), dim3(256), 0, stream,
                           xh, bounds, wlo, twb, nbr_idx, nbr_valid, out, pre, partials);
    }
    hipLaunchKernelGGL(bn_pass1, dim3(128), dim3(256), 0, stream, partials, p2);
    hipLaunchKernelGGL(bn_pass2, dim3(1), dim3(128), 0, stream, p2, gamma, beta, bn);
    if (bf16pre) {
        hipLaunchKernelGGL(bn_silu_bf16_kernel, dim3(2048), dim3(256), 0, stream, pre, out, bn);
    } else {
        hipLaunchKernelGGL(bn_silu_f32_kernel, dim3(2048), dim3(256), 0, stream, out, bn);
    }
}